// Round 8
// baseline (148.775 us; speedup 1.0000x reference)
//
#include <hip/hip_runtime.h>

// YOLO-v1 style loss, persistent-grid fused pass + small final reduce.
// pred: (8192,7,7,30) f32, gt: (8192,7,7,30) f32 -> scalar f32 (= total/8192).
//
// R6 post-mortem: ~31us main vs 15.3us HBM floor. Causes: 2.45 waves-of-
// blocks (fractional tail -> idle CUs) + no overlap of staging with compute.
// R7: persistent 1280 blocks (5/CU via 30KB LDS), each block loops 2-3 tiles
// with register double-buffer: regs->LDS, barrier, ISSUE NEXT TILE'S LOADS,
// compute current from LDS, barrier. Static reg indices (no spill, rule #20);
// __launch_bounds__(128,2) -> 256 VGPR budget.
// (R7 bench was lost to GPUAcquisitionTimeout; identical resubmission.)

#define NCH 30
#define TPB 128
#define CELLS 128
#define TILE_F (CELLS * NCH)      // 3840 floats = 960 float4
#define NBLK 1280                 // 5 blocks/CU * 256 CU
#define INV_B (1.0f / 8192.0f)

__global__ __launch_bounds__(TPB, 2)
void yolo_main(const float* __restrict__ pred,
               const float* __restrict__ gt,
               float* __restrict__ partial,
               int ntiles)
{
    __shared__ float sp[TILE_F];   // 15360 B linear pred tile
    __shared__ float sg[TILE_F];   // 15360 B linear gt tile
    __shared__ float wsum[TPB / 64];

    const int tid = threadIdx.x;
    const int bid = blockIdx.x;

    float4 rp[8], rg[8];           // in-flight tile (static indices only)

    // ---- coalesced tile load into registers: 7 full rounds + tid<64 round
#define LOADT(t)                                                          \
    {                                                                     \
        const float4* gp4 = (const float4*)(pred + (long long)(t) * TILE_F); \
        const float4* gg4 = (const float4*)(gt   + (long long)(t) * TILE_F); \
        _Pragma("unroll")                                                 \
        for (int i = 0; i < 7; ++i) {                                     \
            rp[i] = gp4[tid + i * TPB];                                   \
            rg[i] = gg4[tid + i * TPB];                                   \
        }                                                                 \
        if (tid < 64) {                                                   \
            rp[7] = gp4[tid + 7 * TPB];                                   \
            rg[7] = gg4[tid + 7 * TPB];                                   \
        }                                                                 \
    }

    float acc = 0.0f;
    int t = bid;
    if (t < ntiles) LOADT(t);

    while (t < ntiles) {
        // ---- regs -> LDS (linear)
        float4* lp4 = (float4*)sp;
        float4* lg4 = (float4*)sg;
#pragma unroll
        for (int i = 0; i < 7; ++i) {
            lp4[tid + i * TPB] = rp[i];
            lg4[tid + i * TPB] = rg[i];
        }
        if (tid < 64) {
            lp4[tid + 7 * TPB] = rp[7];
            lg4[tid + 7 * TPB] = rg[7];
        }
        __syncthreads();

        // ---- issue next tile's loads NOW; they fly during compute below
        const int tn = t + NBLK;
        if (tn < ntiles) LOADT(tn);

        // ---- per-cell loss from LDS (verified math, absmax==0 R1-R6)
        {
            const float2* cp = (const float2*)(sp + tid * NCH);
            const float2* cg = (const float2*)(sg + tid * NCH);

            float2 p[15];
#pragma unroll
            for (int j = 0; j < 15; ++j) p[j] = cp[j];

            const float2 g0 = cg[0];
            const float2 g1 = cg[1];
            const float2 g2 = cg[2];          // .x = obj flag
            float2 gcl[10];
#pragma unroll
            for (int j = 0; j < 10; ++j) gcl[j] = cg[5 + j];

            const float gx = g0.x, gy = g0.y, gw = g1.x, gh = g1.y;
            const float gc = g2.x;
            const float obj   = (gc > 0.0f) ? 1.0f : 0.0f;
            const float noobj = (gc == 0.0f) ? 1.0f : 0.0f;

            const float ghw = 3.5f * gw, ghh = 3.5f * gh;   // 0.5*GRID*wh
            const float a2 = 49.0f * gw * gh;

            const float px[2] = {p[0].x, p[2].y};
            const float py[2] = {p[0].y, p[3].x};
            const float pw[2] = {p[1].x, p[3].y};
            const float ph[2] = {p[1].y, p[4].x};
            const float pc[2] = {p[2].x, p[4].y};

            float iou[2];
#pragma unroll
            for (int k = 0; k < 2; ++k) {
                const float phw = 3.5f * pw[k], phh = 3.5f * ph[k];
                const float ltx = fmaxf(px[k] - phw, gx - ghw);
                const float rbx = fminf(px[k] + phw, gx + ghw);
                const float lty = fmaxf(py[k] - phh, gy - ghh);
                const float rby = fminf(py[k] + phh, gy + ghh);
                const float w = fmaxf(rbx - ltx, 0.0f);
                const float h = fmaxf(rby - lty, 0.0f);
                const float inter = w * h;
                const float a1 = 49.0f * pw[k] * ph[k];
                iou[k] = inter / (a1 + a2 - inter);
            }

            // argmax first-max tie-break: box1 wins only if strictly greater
            const int r = (iou[1] > iou[0]) ? 1 : 0;
            const float max_iou = fmaxf(iou[0], iou[1]);

            const float dx = px[r] - gx;
            const float dy = py[r] - gy;
            const float dw = sqrtf(pw[r]) - sqrtf(gw);
            const float dh = sqrtf(ph[r]) - sqrtf(gh);
            const float coord = dx * dx + dy * dy + dw * dw + dh * dh;

            const float d = pc[r] - max_iou;
            const float resp_l = d * d;
            const float irr_l = pc[1 - r] * pc[1 - r];

            const float d0 = pc[0] - gc, d1 = pc[1] - gc;
            const float noobj_l = d0 * d0 + d1 * d1;

            float cls = 0.0f;
#pragma unroll
            for (int j = 0; j < 10; ++j) {
                const float ex = p[5 + j].x - gcl[j].x;
                const float ey = p[5 + j].y - gcl[j].y;
                cls += ex * ex + ey * ey;
            }

            // total = 5*coord + 2*resp + 0.5*noobj + cls + irr (resp x2)
            acc += obj * (5.0f * coord + 2.0f * resp_l + irr_l + cls)
                 + noobj * 0.5f * noobj_l;
        }
        __syncthreads();   // all LDS reads done before next overwrite
        t = tn;
    }

    // ---- reduce: wave64 shuffle -> block -> plain store (no atomic)
    float v = acc;
#pragma unroll
    for (int off = 32; off > 0; off >>= 1)
        v += __shfl_down(v, off, 64);
    if ((tid & 63) == 0) wsum[tid >> 6] = v;
    __syncthreads();
    if (tid == 0)
        partial[bid] = wsum[0] + wsum[1];
}

__global__ __launch_bounds__(256)
void yolo_reduce(const float* __restrict__ partial,
                 float* __restrict__ out,
                 int n)
{
    __shared__ float wsum[4];
    const int tid = threadIdx.x;

    float s = 0.0f;
    for (int i = tid; i < n; i += 256)
        s += partial[i];

#pragma unroll
    for (int off = 32; off > 0; off >>= 1)
        s += __shfl_down(s, off, 64);
    if ((tid & 63) == 0) wsum[tid >> 6] = s;
    __syncthreads();
    if (tid == 0) {
        float t = wsum[0] + wsum[1] + wsum[2] + wsum[3];
        out[0] = t * INV_B;
    }
}

extern "C" void kernel_launch(void* const* d_in, const int* in_sizes, int n_in,
                              void* d_out, int out_size, void* d_ws, size_t ws_size,
                              hipStream_t stream)
{
    const float* pred = (const float*)d_in[0];
    const float* gt   = (const float*)d_in[1];
    float* out = (float*)d_out;
    float* partial = (float*)d_ws;

    const int ncells = in_sizes[0] / NCH;    // 8192*49 = 401408
    const int ntiles = ncells / CELLS;       // 3136 exact
    const int nblocks = (ntiles < NBLK) ? ntiles : NBLK;   // 1280

    yolo_main<<<nblocks, TPB, 0, stream>>>(pred, gt, partial, ntiles);
    yolo_reduce<<<1, 256, 0, stream>>>(partial, out, nblocks);
}

// Round 9
// 114.665 us; speedup vs baseline: 1.2975x; 1.2975x over previous
//
#include <hip/hip_runtime.h>

// YOLO-v1 style loss, persistent grid + global_load_lds DMA double-buffer.
// pred: (8192,7,7,30) f32, gt: (8192,7,7,30) f32 -> scalar f32 (= total/8192).
//
// R8 post-mortem: VGPR-staged double buffer spilled (WRITE_SIZE=94MB = one
// tensor pass through scratch). R9: DMA double-buffer -- global_load_lds has
// NO dest VGPRs (nothing to spill). Persistent 512 blocks (2/CU via 61.4KB
// LDS). Per tile: wave0 DMAs pred (15 x 1KB chunks), wave1 DMAs gt (15).
// Loop: issue next tile's DMA into bufB; s_waitcnt vmcnt(15) (drain current
// tile's 15, keep next 15 in flight -- counted-vmcnt T4, NOT vmcnt(0));
// raw s_barrier; compute bufA; s_barrier; flip. Fetch(t+1) overlaps
// compute(t); no block churn.

#define NCH 30
#define TPB 128
#define CELLS 128
#define TILE_F (CELLS * NCH)      // 3840 floats = 15360 B per tensor
#define NBLK 512                  // 2 blocks/CU * 256 CU
#define INV_B (1.0f / 8192.0f)

typedef __attribute__((address_space(1))) void gvoid_t;
typedef __attribute__((address_space(3))) void lvoid_t;

__device__ __forceinline__ void gload16(const void* g, void* l) {
    __builtin_amdgcn_global_load_lds((gvoid_t*)g, (lvoid_t*)l, 16, 0, 0);
}

__global__ __launch_bounds__(TPB)
void yolo_main(const float* __restrict__ pred,
               const float* __restrict__ gt,
               float* __restrict__ partial,
               int ntiles)
{
    // buf[b][0] = pred tile, buf[b][1] = gt tile
    __shared__ float buf[2][2][TILE_F];   // 61440 B -> 2 blocks/CU
    __shared__ float wsum[TPB / 64];

    const int tid  = threadIdx.x;
    const int lane = tid & 63;
    const int wave = tid >> 6;            // 0: pred DMA, 1: gt DMA
    const int bid  = blockIdx.x;

    // Per-wave DMA of one tile into chosen buffer: 15 x 1KB chunks.
    // Each chunk: one gload_lds instr, lane i moves bytes [i*16, i*16+16).
#define ISSUE_TILE(t, b)                                                   \
    {                                                                      \
        const char* gsrc = (const char*)((wave == 0 ? pred : gt)           \
                          + (long long)(t) * TILE_F);                      \
        char* ldst = (char*)buf[b][wave];                                  \
        _Pragma("unroll")                                                  \
        for (int c = 0; c < 15; ++c) {                                     \
            const int off = c * 1024 + lane * 16;                          \
            gload16(gsrc + off, ldst + off);                               \
        }                                                                  \
    }

    float acc = 0.0f;
    int t = bid;
    int cur = 0;

    if (t < ntiles) ISSUE_TILE(t, 0);     // prologue: 15 loads in flight

    while (t < ntiles) {
        const int tn = t + NBLK;

        // ---- 1. issue next tile's DMA into the other buffer (safe: that
        // buffer was fully read + barrier'd in the previous iteration)
        if (tn < ntiles) {
            ISSUE_TILE(tn, cur ^ 1);
            // drain current tile's 15, keep next tile's 15 in flight
            asm volatile("s_waitcnt vmcnt(15)" ::: "memory");
        } else {
            asm volatile("s_waitcnt vmcnt(0)" ::: "memory");
        }
        __builtin_amdgcn_s_barrier();     // current tile visible to all waves

        // ---- 2. per-cell loss from LDS (verified math, absmax==0 R1-R8)
        {
            const float2* cp = (const float2*)(&buf[cur][0][0] + tid * NCH);
            const float2* cg = (const float2*)(&buf[cur][1][0] + tid * NCH);

            float2 p[15];
#pragma unroll
            for (int j = 0; j < 15; ++j) p[j] = cp[j];

            const float2 g0 = cg[0];
            const float2 g1 = cg[1];
            const float2 g2 = cg[2];          // .x = obj flag
            float2 gcl[10];
#pragma unroll
            for (int j = 0; j < 10; ++j) gcl[j] = cg[5 + j];

            const float gx = g0.x, gy = g0.y, gw = g1.x, gh = g1.y;
            const float gc = g2.x;
            const float obj   = (gc > 0.0f) ? 1.0f : 0.0f;
            const float noobj = (gc == 0.0f) ? 1.0f : 0.0f;

            const float ghw = 3.5f * gw, ghh = 3.5f * gh;   // 0.5*GRID*wh
            const float a2 = 49.0f * gw * gh;

            const float px[2] = {p[0].x, p[2].y};
            const float py[2] = {p[0].y, p[3].x};
            const float pw[2] = {p[1].x, p[3].y};
            const float ph[2] = {p[1].y, p[4].x};
            const float pc[2] = {p[2].x, p[4].y};

            float iou[2];
#pragma unroll
            for (int k = 0; k < 2; ++k) {
                const float phw = 3.5f * pw[k], phh = 3.5f * ph[k];
                const float ltx = fmaxf(px[k] - phw, gx - ghw);
                const float rbx = fminf(px[k] + phw, gx + ghw);
                const float lty = fmaxf(py[k] - phh, gy - ghh);
                const float rby = fminf(py[k] + phh, gy + ghh);
                const float w = fmaxf(rbx - ltx, 0.0f);
                const float h = fmaxf(rby - lty, 0.0f);
                const float inter = w * h;
                const float a1 = 49.0f * pw[k] * ph[k];
                iou[k] = inter / (a1 + a2 - inter);
            }

            // argmax first-max tie-break: box1 wins only if strictly greater
            const int r = (iou[1] > iou[0]) ? 1 : 0;
            const float max_iou = fmaxf(iou[0], iou[1]);

            const float dx = px[r] - gx;
            const float dy = py[r] - gy;
            const float dw = sqrtf(pw[r]) - sqrtf(gw);
            const float dh = sqrtf(ph[r]) - sqrtf(gh);
            const float coord = dx * dx + dy * dy + dw * dw + dh * dh;

            const float d = pc[r] - max_iou;
            const float resp_l = d * d;
            const float irr_l = pc[1 - r] * pc[1 - r];

            const float d0 = pc[0] - gc, d1 = pc[1] - gc;
            const float noobj_l = d0 * d0 + d1 * d1;

            float cls = 0.0f;
#pragma unroll
            for (int j = 0; j < 10; ++j) {
                const float ex = p[5 + j].x - gcl[j].x;
                const float ey = p[5 + j].y - gcl[j].y;
                cls += ex * ex + ey * ey;
            }

            // total = 5*coord + 2*resp + 0.5*noobj + cls + irr (resp x2)
            acc += obj * (5.0f * coord + 2.0f * resp_l + irr_l + cls)
                 + noobj * 0.5f * noobj_l;
        }

        // ---- 3. all reads of buf[cur] done before next iter DMAs into it
        __builtin_amdgcn_s_barrier();
        t = tn;
        cur ^= 1;
    }

    // ---- reduce: wave64 shuffle -> block -> plain store (no atomic)
    float v = acc;
#pragma unroll
    for (int off = 32; off > 0; off >>= 1)
        v += __shfl_down(v, off, 64);
    if ((tid & 63) == 0) wsum[tid >> 6] = v;
    __syncthreads();
    if (tid == 0)
        partial[bid] = wsum[0] + wsum[1];
}

__global__ __launch_bounds__(256)
void yolo_reduce(const float* __restrict__ partial,
                 float* __restrict__ out,
                 int n)
{
    __shared__ float wsum[4];
    const int tid = threadIdx.x;

    float s = 0.0f;
    for (int i = tid; i < n; i += 256)
        s += partial[i];

#pragma unroll
    for (int off = 32; off > 0; off >>= 1)
        s += __shfl_down(s, off, 64);
    if ((tid & 63) == 0) wsum[tid >> 6] = s;
    __syncthreads();
    if (tid == 0) {
        float t = wsum[0] + wsum[1] + wsum[2] + wsum[3];
        out[0] = t * INV_B;
    }
}

extern "C" void kernel_launch(void* const* d_in, const int* in_sizes, int n_in,
                              void* d_out, int out_size, void* d_ws, size_t ws_size,
                              hipStream_t stream)
{
    const float* pred = (const float*)d_in[0];
    const float* gt   = (const float*)d_in[1];
    float* out = (float*)d_out;
    float* partial = (float*)d_ws;

    const int ncells = in_sizes[0] / NCH;    // 8192*49 = 401408
    const int ntiles = ncells / CELLS;       // 3136 exact
    const int nblocks = (ntiles < NBLK) ? ntiles : NBLK;   // 512

    yolo_main<<<nblocks, TPB, 0, stream>>>(pred, gt, partial, ntiles);
    yolo_reduce<<<1, 256, 0, stream>>>(partial, out, nblocks);
}

// Round 10
// 113.420 us; speedup vs baseline: 1.3117x; 1.0110x over previous
//
#include <hip/hip_runtime.h>

// YOLO-v1 style loss, fused single pass + separate final reduce.
// pred: (8192,7,7,30) f32, gt: (8192,7,7,30) f32 -> scalar f32 (= total/8192).
//
// FINAL (R6 structure, best measured: 113.2us total, main ~31us).
// Nine-round synthesis: this environment's HBM READ path ceils at ~3.1 TB/s
// (copy ubench = 3.15R+3.15W, fills = 6.5 W-only; scatter/VGPR/DMA/spill
// structures all converge at 2.6-3.1 R). 96.4 MB irreducible read / 3.1 TB/s
// ~= 31 us = this kernel's measured main duration -> at the read roofline.
// Structure: coalesced float4->LDS transpose (30KB -> 5 blocks/CU, 10
// waves/CU), spill-proof pipelined staging (unroll 4, no guards except the
// tid<64 half-round), per-cell math from LDS (stride-30 float2, benign 4-way
// conflict), no same-address atomics (partials + tiny reduce kernel).

#define NCH 30
#define TPB 128
#define CELLS 128
#define NV4 ((CELLS * NCH) / 4)   // 960 float4 per tensor per block
#define INV_B (1.0f / 8192.0f)

__global__ __launch_bounds__(TPB, 2)
void yolo_main(const float* __restrict__ pred,
               const float* __restrict__ gt,
               float* __restrict__ partial)
{
    __shared__ float sp[CELLS * NCH];   // 15360 B linear pred tile
    __shared__ float sg[CELLS * NCH];   // 15360 B linear gt tile
    __shared__ float wsum[TPB / 64];

    const int tid = threadIdx.x;
    const long long baseF = (long long)blockIdx.x * CELLS * NCH;

    const float4* gp4 = (const float4*)(pred + baseF);
    const float4* gg4 = (const float4*)(gt + baseF);
    float4* lp4 = (float4*)sp;
    float4* lg4 = (float4*)sg;

    // ---- stage: 960 float4 per tensor. 7 full rounds + half round (tid<64).
    // Pipelined copy, bounded live registers (no spill).
#pragma unroll 4
    for (int i = 0; i < 7; ++i) {
        const int idx = tid + i * TPB;
        const float4 a = gp4[idx];
        const float4 b = gg4[idx];
        lp4[idx] = a;
        lg4[idx] = b;
    }
    if (tid < 64) {
        const int idx = tid + 7 * TPB;
        const float4 a = gp4[idx];
        const float4 b = gg4[idx];
        lp4[idx] = a;
        lg4[idx] = b;
    }
    __syncthreads();

    // ---- per-cell loss (verified math, absmax == 0 across R1-R9)
    const float2* cp = (const float2*)(sp + tid * NCH);
    const float2* cg = (const float2*)(sg + tid * NCH);

    float2 p[15];
#pragma unroll
    for (int j = 0; j < 15; ++j) p[j] = cp[j];

    const float2 g0 = cg[0];
    const float2 g1 = cg[1];
    const float2 g2 = cg[2];          // .x = obj flag
    float2 gcl[10];
#pragma unroll
    for (int j = 0; j < 10; ++j) gcl[j] = cg[5 + j];

    const float gx = g0.x, gy = g0.y, gw = g1.x, gh = g1.y;
    const float gc = g2.x;
    const float obj   = (gc > 0.0f) ? 1.0f : 0.0f;
    const float noobj = (gc == 0.0f) ? 1.0f : 0.0f;

    const float ghw = 3.5f * gw, ghh = 3.5f * gh;   // 0.5*GRID*wh
    const float a2 = 49.0f * gw * gh;

    const float px[2] = {p[0].x, p[2].y};
    const float py[2] = {p[0].y, p[3].x};
    const float pw[2] = {p[1].x, p[3].y};
    const float ph[2] = {p[1].y, p[4].x};
    const float pc[2] = {p[2].x, p[4].y};

    float iou[2];
#pragma unroll
    for (int k = 0; k < 2; ++k) {
        const float phw = 3.5f * pw[k], phh = 3.5f * ph[k];
        const float ltx = fmaxf(px[k] - phw, gx - ghw);
        const float rbx = fminf(px[k] + phw, gx + ghw);
        const float lty = fmaxf(py[k] - phh, gy - ghh);
        const float rby = fminf(py[k] + phh, gy + ghh);
        const float w = fmaxf(rbx - ltx, 0.0f);
        const float h = fmaxf(rby - lty, 0.0f);
        const float inter = w * h;
        const float a1 = 49.0f * pw[k] * ph[k];
        iou[k] = inter / (a1 + a2 - inter);
    }

    // argmax first-max tie-break: box1 wins only if strictly greater
    const int r = (iou[1] > iou[0]) ? 1 : 0;
    const float max_iou = fmaxf(iou[0], iou[1]);

    const float dx = px[r] - gx;
    const float dy = py[r] - gy;
    const float dw = sqrtf(pw[r]) - sqrtf(gw);
    const float dh = sqrtf(ph[r]) - sqrtf(gh);
    const float coord = dx * dx + dy * dy + dw * dw + dh * dh;

    const float d = pc[r] - max_iou;
    const float resp_l = d * d;
    const float irr_l = pc[1 - r] * pc[1 - r];

    const float d0 = pc[0] - gc, d1 = pc[1] - gc;
    const float noobj_l = d0 * d0 + d1 * d1;

    float cls = 0.0f;
#pragma unroll
    for (int j = 0; j < 10; ++j) {
        const float ex = p[5 + j].x - gcl[j].x;
        const float ey = p[5 + j].y - gcl[j].y;
        cls += ex * ex + ey * ey;
    }

    // total = 5*coord + 2*resp + 0.5*noobj + cls + irr (resp counted twice)
    const float cell_loss = obj * (5.0f * coord + 2.0f * resp_l + irr_l + cls)
                          + noobj * 0.5f * noobj_l;

    // ---- reduce: wave64 shuffle -> block -> plain store (no atomic)
    float v = cell_loss;
#pragma unroll
    for (int off = 32; off > 0; off >>= 1)
        v += __shfl_down(v, off, 64);
    if ((tid & 63) == 0) wsum[tid >> 6] = v;
    __syncthreads();
    if (tid == 0) {
        float s = 0.0f;
#pragma unroll
        for (int w = 0; w < TPB / 64; ++w) s += wsum[w];
        partial[blockIdx.x] = s;
    }
}

__global__ __launch_bounds__(256)
void yolo_reduce(const float* __restrict__ partial,
                 float* __restrict__ out,
                 int n)
{
    __shared__ float wsum[4];
    const int tid = threadIdx.x;

    float s = 0.0f;
    for (int i = tid; i < n; i += 256)
        s += partial[i];

#pragma unroll
    for (int off = 32; off > 0; off >>= 1)
        s += __shfl_down(s, off, 64);
    if ((tid & 63) == 0) wsum[tid >> 6] = s;
    __syncthreads();
    if (tid == 0) {
        float t = wsum[0] + wsum[1] + wsum[2] + wsum[3];
        out[0] = t * INV_B;
    }
}

extern "C" void kernel_launch(void* const* d_in, const int* in_sizes, int n_in,
                              void* d_out, int out_size, void* d_ws, size_t ws_size,
                              hipStream_t stream)
{
    const float* pred = (const float*)d_in[0];
    const float* gt   = (const float*)d_in[1];
    float* out = (float*)d_out;
    float* partial = (float*)d_ws;

    const int ncells = in_sizes[0] / NCH;   // 8192*49 = 401408
    const int nblocks = ncells / CELLS;     // 3136 exact

    yolo_main<<<nblocks, TPB, 0, stream>>>(pred, gt, partial);
    yolo_reduce<<<1, 256, 0, stream>>>(partial, out, nblocks);
}